// Round 2
// baseline (1963.196 us; speedup 1.0000x reference)
//
#include <hip/hip_runtime.h>
#include <hip/hip_bf16.h>

// Problem constants
#define BB 8
#define SS 4096
#define DD 2048
#define HH 16
#define HDIM 128
#define LL 16
#define JJ 256           // HH*LL, j = h*16 + l
#define ROWS (BB*SS)     // 32768
#define LN_EPS 1e-5f

typedef __attribute__((ext_vector_type(8))) short short8;
typedef __attribute__((ext_vector_type(4))) float f32x4;

__device__ __forceinline__ unsigned short f2bf(float f) {
  unsigned int u = __builtin_bit_cast(unsigned int, f);
  u += 0x7fffu + ((u >> 16) & 1u);        // round-to-nearest-even
  return (unsigned short)(u >> 16);
}

// ---------------------------------------------------------------- q[l][c] = b_lq[c] + sum_e latents[l][e] w_lq[e][c]
__global__ __launch_bounds__(256) void k_q(const float* latents, const float* w_lq,
                                           const float* b_lq, float* q) {
  int c = blockIdx.x * 256 + threadIdx.x;   // grid 8 -> c in 0..2047
  float acc[16];
#pragma unroll
  for (int l = 0; l < 16; ++l) acc[l] = 0.f;
  for (int e = 0; e < 2048; ++e) {
    float w = w_lq[(size_t)e * 2048 + c];
#pragma unroll
    for (int l = 0; l < 16; ++l) acc[l] += latents[l * 2048 + e] * w;
  }
  float bias = b_lq[c];
#pragma unroll
  for (int l = 0; l < 16; ++l) q[l * 2048 + c] = acc[l] + bias;
}

// ---------------------------------------------------------------- per-row LN stats
__global__ __launch_bounds__(256) void k_stats(const float* x, float* stats) {
  int row = blockIdx.x;                     // 0..32767
  const float* xr = x + (size_t)row * 2048;
  float s = 0.f, s2 = 0.f;
  for (int i = threadIdx.x; i < 512; i += 256) {
    float4 v = ((const float4*)xr)[i];
    s  += v.x + v.y + v.z + v.w;
    s2 += v.x * v.x + v.y * v.y + v.z * v.z + v.w * v.w;
  }
#pragma unroll
  for (int o = 32; o; o >>= 1) { s += __shfl_down(s, o); s2 += __shfl_down(s2, o); }
  __shared__ float red[8];
  int wid = threadIdx.x >> 6;
  if ((threadIdx.x & 63) == 0) { red[wid * 2] = s; red[wid * 2 + 1] = s2; }
  __syncthreads();
  if (threadIdx.x == 0) {
    float ts = 0.f, ts2 = 0.f;
#pragma unroll
    for (int w = 0; w < 4; ++w) { ts += red[w * 2]; ts2 += red[w * 2 + 1]; }
    float mu  = ts * (1.0f / 2048.0f);
    float var = ts2 * (1.0f / 2048.0f) - mu * mu;
    stats[row * 2]     = mu;
    stats[row * 2 + 1] = rsqrtf(var + LN_EPS);
  }
}

// ---------------------------------------------------------------- Wq_t[j][e] = (1/sqrt(128)) * sum_d w_k[e][h*128+d] * q[l][h*128+d]
__global__ __launch_bounds__(256) void k_wq(const float* w_k, const float* q, short* wq_t) {
  int e = blockIdx.x;                       // 0..2047
  __shared__ float wrow[2048];
  for (int i = threadIdx.x; i < 512; i += 256)
    ((float4*)wrow)[i] = ((const float4*)(w_k + (size_t)e * 2048))[i];
  __syncthreads();
  int j = threadIdx.x;
  int h = j >> 4, l = j & 15;
  const float* qrow = q + l * 2048 + h * 128;
  const float* wr = wrow + h * 128;
  float acc = 0.f;
#pragma unroll 8
  for (int d = 0; d < 128; ++d) acc += wr[d] * qrow[d];
  wq_t[(size_t)j * 2048 + e] = (short)f2bf(acc * 0.08838834764831845f);
}

// ---------------------------------------------------------------- scores[b][j][s] = Wq_t @ h^T  (LN fused into B staging)
__global__ __launch_bounds__(256) void k_scores(const float* x, const float* stats,
                                                const float* ln_g, const float* ln_b,
                                                const short* wq_t, float* scores) {
  int s0 = blockIdx.x * 64;                 // s-tile
  int b  = blockIdx.y;
  __shared__ short lA[256 * 72];            // Wq_t tile [j][k], padded
  __shared__ short lB[64 * 72];             // h tile [s][k], padded
  int t = threadIdx.x, lane = t & 63, w = t >> 6;
  f32x4 zero = {0.f, 0.f, 0.f, 0.f};
  f32x4 acc[4][4];
#pragma unroll
  for (int m = 0; m < 4; ++m)
#pragma unroll
    for (int n = 0; n < 4; ++n) acc[m][n] = zero;

  int sr = t >> 2, ec = t & 3;              // B staging: row 0..63, 16-col chunk 0..3
  int grow = b * 4096 + s0 + sr;
  float mu   = stats[grow * 2];
  float rstd = stats[grow * 2 + 1];
  const float* xrow = x + (size_t)grow * 2048;

  for (int k0 = 0; k0 < 2048; k0 += 64) {
    { // stage A: thread t = row j, 64 bf16
      const short8* src = (const short8*)(wq_t + (size_t)t * 2048 + k0);
      short8* dst = (short8*)(lA + t * 72);
#pragma unroll
      for (int i = 0; i < 8; ++i) dst[i] = src[i];
    }
    { // stage B: LN(x) -> bf16
      const float* xsrc = xrow + k0 + ec * 16;
      short8 h0, h1;
#pragma unroll
      for (int i = 0; i < 16; i += 4) {
        float4 v = *(const float4*)(xsrc + i);
        int kk = k0 + ec * 16 + i;
        unsigned short c0 = f2bf((v.x - mu) * rstd * ln_g[kk + 0] + ln_b[kk + 0]);
        unsigned short c1 = f2bf((v.y - mu) * rstd * ln_g[kk + 1] + ln_b[kk + 1]);
        unsigned short c2 = f2bf((v.z - mu) * rstd * ln_g[kk + 2] + ln_b[kk + 2]);
        unsigned short c3 = f2bf((v.w - mu) * rstd * ln_g[kk + 3] + ln_b[kk + 3]);
        if (i < 8) { h0[i+0]=(short)c0; h0[i+1]=(short)c1; h0[i+2]=(short)c2; h0[i+3]=(short)c3; }
        else { h1[i-8]=(short)c0; h1[i-7]=(short)c1; h1[i-6]=(short)c2; h1[i-5]=(short)c3; }
      }
      short8* dstb = (short8*)(lB + sr * 72 + ec * 16);
      dstb[0] = h0; dstb[1] = h1;
    }
    __syncthreads();
#pragma unroll
    for (int kk = 0; kk < 2; ++kk) {
      short8 afr[4];
#pragma unroll
      for (int m = 0; m < 4; ++m)
        afr[m] = *(const short8*)(lA + (w * 64 + m * 16 + (lane & 15)) * 72 + kk * 32 + (lane >> 4) * 8);
#pragma unroll
      for (int n = 0; n < 4; ++n) {
        short8 bfr = *(const short8*)(lB + (n * 16 + (lane & 15)) * 72 + kk * 32 + (lane >> 4) * 8);
#pragma unroll
        for (int m = 0; m < 4; ++m)
          acc[m][n] = __builtin_amdgcn_mfma_f32_16x16x32_bf16(afr[m], bfr, acc[m][n], 0, 0, 0);
      }
    }
    __syncthreads();
  }
  int r4 = (lane >> 4) * 4, cc = lane & 15;
#pragma unroll
  for (int m = 0; m < 4; ++m) {
    int j = w * 64 + m * 16 + r4;
#pragma unroll
    for (int n = 0; n < 4; ++n) {
      int s = s0 + n * 16 + cc;
      float* dst = scores + ((size_t)b * 256 + j) * 4096 + s;
#pragma unroll
      for (int i = 0; i < 4; ++i) dst[(size_t)i * 4096] = acc[m][n][i];
    }
  }
}

// ---------------------------------------------------------------- softmax over s, emit bf16 probs
__global__ __launch_bounds__(256) void k_softmax(const float* scores, short* probs) {
  int j = blockIdx.x, b = blockIdx.y;
  const float* row = scores + ((size_t)b * 256 + j) * 4096;
  float v[16];
  float mx = -1e30f;
#pragma unroll
  for (int i = 0; i < 16; ++i) { v[i] = row[threadIdx.x + 256 * i]; mx = fmaxf(mx, v[i]); }
#pragma unroll
  for (int o = 32; o; o >>= 1) mx = fmaxf(mx, __shfl_xor(mx, o));
  __shared__ float redm[4], reds[4];
  if ((threadIdx.x & 63) == 0) redm[threadIdx.x >> 6] = mx;
  __syncthreads();
  mx = fmaxf(fmaxf(redm[0], redm[1]), fmaxf(redm[2], redm[3]));
  float sum = 0.f;
#pragma unroll
  for (int i = 0; i < 16; ++i) { v[i] = __expf(v[i] - mx); sum += v[i]; }
#pragma unroll
  for (int o = 32; o; o >>= 1) sum += __shfl_xor(sum, o);
  if ((threadIdx.x & 63) == 0) reds[threadIdx.x >> 6] = sum;
  __syncthreads();
  sum = reds[0] + reds[1] + reds[2] + reds[3];
  float inv = 1.0f / sum;
  short* pr = probs + ((size_t)b * 256 + j) * 4096;
#pragma unroll
  for (int i = 0; i < 16; ++i) pr[threadIdx.x + 256 * i] = (short)f2bf(v[i] * inv);
}

// ---------------------------------------------------------------- T[b][j][e] = probs @ h   (h^T staged via transpose, LN fused)
__global__ __launch_bounds__(256) void k_T(const float* x, const float* stats,
                                           const float* ln_g, const float* ln_b,
                                           const short* probs, float* T) {
  int e0 = blockIdx.x * 64;                 // e-tile
  int b  = blockIdx.y;
  __shared__ short lA[256 * 72];            // probs [j][s]
  __shared__ short lB[64 * 72];             // h^T [e][s]
  int t = threadIdx.x, lane = t & 63, w = t >> 6;
  f32x4 zero = {0.f, 0.f, 0.f, 0.f};
  f32x4 acc[4][4];
#pragma unroll
  for (int m = 0; m < 4; ++m)
#pragma unroll
    for (int n = 0; n < 4; ++n) acc[m][n] = zero;

  int sr = t >> 2, ec = t & 3;
  float gg[16], bbv[16];
#pragma unroll
  for (int i = 0; i < 16; ++i) { gg[i] = ln_g[e0 + ec * 16 + i]; bbv[i] = ln_b[e0 + ec * 16 + i]; }

  for (int k0 = 0; k0 < 4096; k0 += 64) {
    { // stage A: probs row j=t, s = k0..k0+63
      const short8* src = (const short8*)(probs + ((size_t)b * 256 + t) * 4096 + k0);
      short8* dst = (short8*)(lA + t * 72);
#pragma unroll
      for (int i = 0; i < 8; ++i) dst[i] = src[i];
    }
    { // stage B transposed with LN: x[b][k0+sr][e0+ec*16 .. +16] -> lB[e][s]
      int grow = b * 4096 + k0 + sr;
      float mu = stats[grow * 2], rstd = stats[grow * 2 + 1];
      const float* xsrc = x + (size_t)grow * 2048 + e0 + ec * 16;
#pragma unroll
      for (int i = 0; i < 16; i += 4) {
        float4 v = *(const float4*)(xsrc + i);
        lB[(ec * 16 + i + 0) * 72 + sr] = (short)f2bf((v.x - mu) * rstd * gg[i + 0] + bbv[i + 0]);
        lB[(ec * 16 + i + 1) * 72 + sr] = (short)f2bf((v.y - mu) * rstd * gg[i + 1] + bbv[i + 1]);
        lB[(ec * 16 + i + 2) * 72 + sr] = (short)f2bf((v.z - mu) * rstd * gg[i + 2] + bbv[i + 2]);
        lB[(ec * 16 + i + 3) * 72 + sr] = (short)f2bf((v.w - mu) * rstd * gg[i + 3] + bbv[i + 3]);
      }
    }
    __syncthreads();
#pragma unroll
    for (int kk = 0; kk < 2; ++kk) {
      short8 afr[4];
#pragma unroll
      for (int m = 0; m < 4; ++m)
        afr[m] = *(const short8*)(lA + (w * 64 + m * 16 + (lane & 15)) * 72 + kk * 32 + (lane >> 4) * 8);
#pragma unroll
      for (int n = 0; n < 4; ++n) {
        short8 bfr = *(const short8*)(lB + (n * 16 + (lane & 15)) * 72 + kk * 32 + (lane >> 4) * 8);
#pragma unroll
        for (int m = 0; m < 4; ++m)
          acc[m][n] = __builtin_amdgcn_mfma_f32_16x16x32_bf16(afr[m], bfr, acc[m][n], 0, 0, 0);
      }
    }
    __syncthreads();
  }
  int r4 = (lane >> 4) * 4, cc = lane & 15;
#pragma unroll
  for (int m = 0; m < 4; ++m) {
    int j = w * 64 + m * 16 + r4;
#pragma unroll
    for (int n = 0; n < 4; ++n) {
      int e = e0 + n * 16 + cc;
      float* dst = T + ((size_t)b * 256 + j) * 2048 + e;
#pragma unroll
      for (int i = 0; i < 4; ++i) dst[(size_t)i * 2048] = acc[m][n][i];
    }
  }
}

// ---------------------------------------------------------------- Tbar[b][h][e] = mean_l T[b][h*16+l][e]
__global__ __launch_bounds__(256) void k_tbar(const float* T, float* Tbar) {
  int b = blockIdx.x >> 4, h = blockIdx.x & 15;
  for (int e = threadIdx.x; e < 2048; e += 256) {
    float s = 0.f;
#pragma unroll
    for (int l = 0; l < 16; ++l) s += T[((size_t)b * 256 + h * 16 + l) * 2048 + e];
    Tbar[((size_t)b * 16 + h) * 2048 + e] = s * (1.0f / 16.0f);
  }
}

// ---------------------------------------------------------------- cbar[b][c] = b_v[c] + sum_e Tbar[b][h(c)][e] * w_v[e][c]
__global__ __launch_bounds__(256) void k_cbar(const float* Tbar, const float* w_v,
                                              const float* b_v, float* cbar) {
  int c = blockIdx.x * 256 + threadIdx.x;   // grid 8
  int h = c >> 7;
  float acc[8];
#pragma unroll
  for (int b = 0; b < 8; ++b) acc[b] = 0.f;
  for (int e = 0; e < 2048; ++e) {
    float wv = w_v[(size_t)e * 2048 + c];
#pragma unroll
    for (int b = 0; b < 8; ++b) acc[b] += Tbar[((size_t)b * 16 + h) * 2048 + e] * wv;
  }
  float bias = b_v[c];
#pragma unroll
  for (int b = 0; b < 8; ++b) cbar[b * 2048 + c] = acc[b] + bias;
}

// ---------------------------------------------------------------- vout[b][c] = bias[c] + sum_e vin[b][e] * W[e][c]
__global__ __launch_bounds__(256) void k_vecmat(const float* vin, const float* W,
                                                const float* bias, float* vout) {
  int c = blockIdx.x * 256 + threadIdx.x;   // grid 8
  float acc[8];
#pragma unroll
  for (int b = 0; b < 8; ++b) acc[b] = 0.f;
  for (int e = 0; e < 2048; ++e) {
    float wv = W[(size_t)e * 2048 + c];
#pragma unroll
    for (int b = 0; b < 8; ++b) acc[b] += vin[b * 2048 + e] * wv;
  }
  float bb = bias[c];
#pragma unroll
  for (int b = 0; b < 8; ++b) vout[b * 2048 + c] = acc[b] + bb;
}

// ---------------------------------------------------------------- out = x + broadcast(outv)   (fp32!)
__global__ __launch_bounds__(256) void k_resid(const float* x, const float* outv, float* out) {
  size_t i4 = (size_t)blockIdx.x * 256 + threadIdx.x;
  size_t total4 = (size_t)ROWS * 512;
  size_t stride = (size_t)gridDim.x * 256;
  for (; i4 < total4; i4 += stride) {
    int b  = (int)(i4 >> 21);               // 4096*512 float4 per batch
    int c4 = (int)(i4 & 511);
    float4 xv = ((const float4*)x)[i4];
    float4 ov = ((const float4*)outv)[b * 512 + c4];
    float4 o;
    o.x = xv.x + ov.x; o.y = xv.y + ov.y;
    o.z = xv.z + ov.z; o.w = xv.w + ov.w;
    ((float4*)out)[i4] = o;
  }
}

// ================================================================ launch
extern "C" void kernel_launch(void* const* d_in, const int* in_sizes, int n_in,
                              void* d_out, int out_size, void* d_ws, size_t ws_size,
                              hipStream_t stream) {
  const float* x       = (const float*)d_in[0];
  const float* ln_g    = (const float*)d_in[1];
  const float* ln_b    = (const float*)d_in[2];
  const float* latents = (const float*)d_in[3];
  const float* w_lq    = (const float*)d_in[4];
  const float* b_lq    = (const float*)d_in[5];
  const float* w_k     = (const float*)d_in[6];
  // const float* b_k  = (const float*)d_in[7];   // softmax-invariant, unused
  const float* w_v     = (const float*)d_in[8];
  const float* b_v     = (const float*)d_in[9];
  const float* w_lv    = (const float*)d_in[10];
  const float* b_lv    = (const float*)d_in[11];
  const float* w_out   = (const float*)d_in[12];
  const float* b_out   = (const float*)d_in[13];

  // d_out is fp32 [8,4096,2048] = 256 MB; its first ~70 MB doubles as scratch,
  // all dead before k_resid overwrites the full buffer. outv lives in d_ws.
  char* base = (char*)d_out;
  float* scores = (float*)(base);                        // 33,554,432 B
  short* probs  = (short*)(base + 33554432);             // 16,777,216 B
  float* T      = (float*)(base + 50331648);             // 16,777,216 B
  float* q      = (float*)(base + 67108864);             //    131,072 B
  short* wq_t   = (short*)(base + 67239936);             //  1,048,576 B
  float* stats  = (float*)(base + 68288512);             //    262,144 B
  float* Tbar   = (float*)(base + 68550656);             //  1,048,576 B
  float* cbar   = (float*)(base + 69599232);             //     65,536 B
  float* pooled = (float*)(base + 69664768);             //     65,536 B
  float* outv   = (float*)d_ws;                          //     65,536 B (read by k_resid)
  float* out    = (float*)d_out;

  k_q      <<<8, 256, 0, stream>>>(latents, w_lq, b_lq, q);
  k_stats  <<<32768, 256, 0, stream>>>(x, stats);
  k_wq     <<<2048, 256, 0, stream>>>(w_k, q, wq_t);
  k_scores <<<dim3(64, 8), 256, 0, stream>>>(x, stats, ln_g, ln_b, wq_t, scores);
  k_softmax<<<dim3(256, 8), 256, 0, stream>>>(scores, probs);
  k_T      <<<dim3(32, 8), 256, 0, stream>>>(x, stats, ln_g, ln_b, probs, T);
  k_tbar   <<<128, 256, 0, stream>>>(T, Tbar);
  k_cbar   <<<8, 256, 0, stream>>>(Tbar, w_v, b_v, cbar);
  k_vecmat <<<8, 256, 0, stream>>>(cbar, w_lv, b_lv, pooled);
  k_vecmat <<<8, 256, 0, stream>>>(pooled, w_out, b_out, outv);
  k_resid  <<<2048, 256, 0, stream>>>(x, outv, out);
}

// Round 3
// 609.838 us; speedup vs baseline: 3.2192x; 3.2192x over previous
//
#include <hip/hip_runtime.h>
#include <hip/hip_bf16.h>

// Problem constants
#define BB 8
#define SS 4096
#define DD 2048
#define HH 16
#define HDIM 128
#define LL 16
#define JJ 256           // HH*LL, j = h*16 + l
#define ROWS (BB*SS)     // 32768
#define LN_EPS 1e-5f

typedef __attribute__((ext_vector_type(8))) short short8;
typedef __attribute__((ext_vector_type(4))) float f32x4;

__device__ __forceinline__ unsigned short f2bf(float f) {
  unsigned int u = __builtin_bit_cast(unsigned int, f);
  u += 0x7fffu + ((u >> 16) & 1u);        // round-to-nearest-even
  return (unsigned short)(u >> 16);
}

// ---------------------------------------------------------------- q partials: qpart[eb][l][c] = sum_{e in chunk} latents[l][e] w_lq[e][c]
__global__ __launch_bounds__(256) void k_q_part(const float* latents, const float* w_lq, float* qpart) {
  int c  = blockIdx.x * 256 + threadIdx.x;  // 0..2047
  int e0 = blockIdx.y * 64;                 // 32 chunks
  float acc[16];
#pragma unroll
  for (int l = 0; l < 16; ++l) acc[l] = 0.f;
  for (int e = e0; e < e0 + 64; ++e) {
    float w = w_lq[(size_t)e * 2048 + c];
#pragma unroll
    for (int l = 0; l < 16; ++l) acc[l] += latents[l * 2048 + e] * w;
  }
#pragma unroll
  for (int l = 0; l < 16; ++l) qpart[((size_t)blockIdx.y * 16 + l) * 2048 + c] = acc[l];
}

// ---------------------------------------------------------------- generic 32-partial reduce: out[r][c] = bias[c] + sum_p part[p][r][c]
__global__ __launch_bounds__(256) void k_reduce(const float* part, const float* bias, float* out, int R) {
  int c = blockIdx.x * 256 + threadIdx.x;   // grid.x = 8
  int r = blockIdx.y;                       // grid.y = R
  float s = bias[c];
  for (int p = 0; p < 32; ++p) s += part[((size_t)p * R + r) * 2048 + c];
  out[r * 2048 + c] = s;
}

// ---------------------------------------------------------------- per-row LN stats
__global__ __launch_bounds__(256) void k_stats(const float* x, float* stats) {
  int row = blockIdx.x;                     // 0..32767
  const float* xr = x + (size_t)row * 2048;
  float s = 0.f, s2 = 0.f;
  for (int i = threadIdx.x; i < 512; i += 256) {
    float4 v = ((const float4*)xr)[i];
    s  += v.x + v.y + v.z + v.w;
    s2 += v.x * v.x + v.y * v.y + v.z * v.z + v.w * v.w;
  }
#pragma unroll
  for (int o = 32; o; o >>= 1) { s += __shfl_down(s, o); s2 += __shfl_down(s2, o); }
  __shared__ float red[8];
  int wid = threadIdx.x >> 6;
  if ((threadIdx.x & 63) == 0) { red[wid * 2] = s; red[wid * 2 + 1] = s2; }
  __syncthreads();
  if (threadIdx.x == 0) {
    float ts = 0.f, ts2 = 0.f;
#pragma unroll
    for (int w = 0; w < 4; ++w) { ts += red[w * 2]; ts2 += red[w * 2 + 1]; }
    float mu  = ts * (1.0f / 2048.0f);
    float var = ts2 * (1.0f / 2048.0f) - mu * mu;
    stats[row * 2]     = mu;
    stats[row * 2 + 1] = rsqrtf(var + LN_EPS);
  }
}

// ---------------------------------------------------------------- Wq_t[j][e] = (1/sqrt(128)) * sum_d w_k[e][h*128+d] * q[l][h*128+d]
__global__ __launch_bounds__(256) void k_wq(const float* w_k, const float* q, short* wq_t) {
  int e = blockIdx.x;                       // 0..2047
  __shared__ float wrow[2048];
  for (int i = threadIdx.x; i < 512; i += 256)
    ((float4*)wrow)[i] = ((const float4*)(w_k + (size_t)e * 2048))[i];
  __syncthreads();
  int j = threadIdx.x;
  int h = j >> 4, l = j & 15;
  const float* qrow = q + l * 2048 + h * 128;
  const float* wr = wrow + h * 128;
  float acc = 0.f;
#pragma unroll 8
  for (int d = 0; d < 128; ++d) acc += wr[d] * qrow[d];
  wq_t[(size_t)j * 2048 + e] = (short)f2bf(acc * 0.08838834764831845f);
}

// ---------------------------------------------------------------- scores[b][j][s] = Wq_t @ h^T  (LN fused into B staging)
__global__ __launch_bounds__(256) void k_scores(const float* x, const float* stats,
                                                const float* ln_g, const float* ln_b,
                                                const short* wq_t, float* scores) {
  int s0 = blockIdx.x * 64;                 // s-tile
  int b  = blockIdx.y;
  __shared__ short lA[256 * 72];            // Wq_t tile [j][k], padded
  __shared__ short lB[64 * 72];             // h tile [s][k], padded
  int t = threadIdx.x, lane = t & 63, w = t >> 6;
  f32x4 zero = {0.f, 0.f, 0.f, 0.f};
  f32x4 acc[4][4];
#pragma unroll
  for (int m = 0; m < 4; ++m)
#pragma unroll
    for (int n = 0; n < 4; ++n) acc[m][n] = zero;

  int sr = t >> 2, ec = t & 3;              // B staging: row 0..63, 16-col chunk 0..3
  int grow = b * 4096 + s0 + sr;
  float mu   = stats[grow * 2];
  float rstd = stats[grow * 2 + 1];
  const float* xrow = x + (size_t)grow * 2048;

  for (int k0 = 0; k0 < 2048; k0 += 64) {
    { // stage A: thread t = row j, 64 bf16
      const short8* src = (const short8*)(wq_t + (size_t)t * 2048 + k0);
      short8* dst = (short8*)(lA + t * 72);
#pragma unroll
      for (int i = 0; i < 8; ++i) dst[i] = src[i];
    }
    { // stage B: LN(x) -> bf16
      const float* xsrc = xrow + k0 + ec * 16;
      short8 h0, h1;
#pragma unroll
      for (int i = 0; i < 16; i += 4) {
        float4 v = *(const float4*)(xsrc + i);
        int kk = k0 + ec * 16 + i;
        unsigned short c0 = f2bf((v.x - mu) * rstd * ln_g[kk + 0] + ln_b[kk + 0]);
        unsigned short c1 = f2bf((v.y - mu) * rstd * ln_g[kk + 1] + ln_b[kk + 1]);
        unsigned short c2 = f2bf((v.z - mu) * rstd * ln_g[kk + 2] + ln_b[kk + 2]);
        unsigned short c3 = f2bf((v.w - mu) * rstd * ln_g[kk + 3] + ln_b[kk + 3]);
        if (i < 8) { h0[i+0]=(short)c0; h0[i+1]=(short)c1; h0[i+2]=(short)c2; h0[i+3]=(short)c3; }
        else { h1[i-8]=(short)c0; h1[i-7]=(short)c1; h1[i-6]=(short)c2; h1[i-5]=(short)c3; }
      }
      short8* dstb = (short8*)(lB + sr * 72 + ec * 16);
      dstb[0] = h0; dstb[1] = h1;
    }
    __syncthreads();
#pragma unroll
    for (int kk = 0; kk < 2; ++kk) {
      short8 afr[4];
#pragma unroll
      for (int m = 0; m < 4; ++m)
        afr[m] = *(const short8*)(lA + (w * 64 + m * 16 + (lane & 15)) * 72 + kk * 32 + (lane >> 4) * 8);
#pragma unroll
      for (int n = 0; n < 4; ++n) {
        short8 bfr = *(const short8*)(lB + (n * 16 + (lane & 15)) * 72 + kk * 32 + (lane >> 4) * 8);
#pragma unroll
        for (int m = 0; m < 4; ++m)
          acc[m][n] = __builtin_amdgcn_mfma_f32_16x16x32_bf16(afr[m], bfr, acc[m][n], 0, 0, 0);
      }
    }
    __syncthreads();
  }
  int r4 = (lane >> 4) * 4, cc = lane & 15;
#pragma unroll
  for (int m = 0; m < 4; ++m) {
    int j = w * 64 + m * 16 + r4;
#pragma unroll
    for (int n = 0; n < 4; ++n) {
      int s = s0 + n * 16 + cc;
      float* dst = scores + ((size_t)b * 256 + j) * 4096 + s;
#pragma unroll
      for (int i = 0; i < 4; ++i) dst[(size_t)i * 4096] = acc[m][n][i];
    }
  }
}

// ---------------------------------------------------------------- softmax over s, emit bf16 probs
__global__ __launch_bounds__(256) void k_softmax(const float* scores, short* probs) {
  int j = blockIdx.x, b = blockIdx.y;
  const float* row = scores + ((size_t)b * 256 + j) * 4096;
  float v[16];
  float mx = -1e30f;
#pragma unroll
  for (int i = 0; i < 16; ++i) { v[i] = row[threadIdx.x + 256 * i]; mx = fmaxf(mx, v[i]); }
#pragma unroll
  for (int o = 32; o; o >>= 1) mx = fmaxf(mx, __shfl_xor(mx, o));
  __shared__ float redm[4], reds[4];
  if ((threadIdx.x & 63) == 0) redm[threadIdx.x >> 6] = mx;
  __syncthreads();
  mx = fmaxf(fmaxf(redm[0], redm[1]), fmaxf(redm[2], redm[3]));
  float sum = 0.f;
#pragma unroll
  for (int i = 0; i < 16; ++i) { v[i] = __expf(v[i] - mx); sum += v[i]; }
#pragma unroll
  for (int o = 32; o; o >>= 1) sum += __shfl_xor(sum, o);
  if ((threadIdx.x & 63) == 0) reds[threadIdx.x >> 6] = sum;
  __syncthreads();
  sum = reds[0] + reds[1] + reds[2] + reds[3];
  float inv = 1.0f / sum;
  short* pr = probs + ((size_t)b * 256 + j) * 4096;
#pragma unroll
  for (int i = 0; i < 16; ++i) pr[threadIdx.x + 256 * i] = (short)f2bf(v[i] * inv);
}

// ---------------------------------------------------------------- T[b][j][e] = probs @ h   (h^T staged via transpose, LN fused)
__global__ __launch_bounds__(256) void k_T(const float* x, const float* stats,
                                           const float* ln_g, const float* ln_b,
                                           const short* probs, float* T) {
  int e0 = blockIdx.x * 64;                 // e-tile
  int b  = blockIdx.y;
  __shared__ short lA[256 * 72];            // probs [j][s]
  __shared__ short lB[64 * 72];             // h^T [e][s]
  int t = threadIdx.x, lane = t & 63, w = t >> 6;
  f32x4 zero = {0.f, 0.f, 0.f, 0.f};
  f32x4 acc[4][4];
#pragma unroll
  for (int m = 0; m < 4; ++m)
#pragma unroll
    for (int n = 0; n < 4; ++n) acc[m][n] = zero;

  int sr = t >> 2, ec = t & 3;
  float gg[16], bbv[16];
#pragma unroll
  for (int i = 0; i < 16; ++i) { gg[i] = ln_g[e0 + ec * 16 + i]; bbv[i] = ln_b[e0 + ec * 16 + i]; }

  for (int k0 = 0; k0 < 4096; k0 += 64) {
    { // stage A: probs row j=t, s = k0..k0+63
      const short8* src = (const short8*)(probs + ((size_t)b * 256 + t) * 4096 + k0);
      short8* dst = (short8*)(lA + t * 72);
#pragma unroll
      for (int i = 0; i < 8; ++i) dst[i] = src[i];
    }
    { // stage B transposed with LN: x[b][k0+sr][e0+ec*16 .. +16] -> lB[e][s]
      int grow = b * 4096 + k0 + sr;
      float mu = stats[grow * 2], rstd = stats[grow * 2 + 1];
      const float* xsrc = x + (size_t)grow * 2048 + e0 + ec * 16;
#pragma unroll
      for (int i = 0; i < 16; i += 4) {
        float4 v = *(const float4*)(xsrc + i);
        lB[(ec * 16 + i + 0) * 72 + sr] = (short)f2bf((v.x - mu) * rstd * gg[i + 0] + bbv[i + 0]);
        lB[(ec * 16 + i + 1) * 72 + sr] = (short)f2bf((v.y - mu) * rstd * gg[i + 1] + bbv[i + 1]);
        lB[(ec * 16 + i + 2) * 72 + sr] = (short)f2bf((v.z - mu) * rstd * gg[i + 2] + bbv[i + 2]);
        lB[(ec * 16 + i + 3) * 72 + sr] = (short)f2bf((v.w - mu) * rstd * gg[i + 3] + bbv[i + 3]);
      }
    }
    __syncthreads();
#pragma unroll
    for (int kk = 0; kk < 2; ++kk) {
      short8 afr[4];
#pragma unroll
      for (int m = 0; m < 4; ++m)
        afr[m] = *(const short8*)(lA + (w * 64 + m * 16 + (lane & 15)) * 72 + kk * 32 + (lane >> 4) * 8);
#pragma unroll
      for (int n = 0; n < 4; ++n) {
        short8 bfr = *(const short8*)(lB + (n * 16 + (lane & 15)) * 72 + kk * 32 + (lane >> 4) * 8);
#pragma unroll
        for (int m = 0; m < 4; ++m)
          acc[m][n] = __builtin_amdgcn_mfma_f32_16x16x32_bf16(afr[m], bfr, acc[m][n], 0, 0, 0);
      }
    }
    __syncthreads();
  }
  int r4 = (lane >> 4) * 4, cc = lane & 15;
#pragma unroll
  for (int m = 0; m < 4; ++m) {
    int j = w * 64 + m * 16 + r4;
#pragma unroll
    for (int n = 0; n < 4; ++n) {
      int e = e0 + n * 16 + cc;
      float* dst = T + ((size_t)b * 256 + j) * 2048 + e;
#pragma unroll
      for (int i = 0; i < 4; ++i) dst[(size_t)i * 2048] = acc[m][n][i];
    }
  }
}

// ---------------------------------------------------------------- Tbar[b][h][e] = mean_l T[b][h*16+l][e]
__global__ __launch_bounds__(256) void k_tbar(const float* T, float* Tbar) {
  int b = blockIdx.x >> 4, h = blockIdx.x & 15;
  for (int e = threadIdx.x; e < 2048; e += 256) {
    float s = 0.f;
#pragma unroll
    for (int l = 0; l < 16; ++l) s += T[((size_t)b * 256 + h * 16 + l) * 2048 + e];
    Tbar[((size_t)b * 16 + h) * 2048 + e] = s * (1.0f / 16.0f);
  }
}

// ---------------------------------------------------------------- cbar partials over e: part[eb][b][c]
__global__ __launch_bounds__(256) void k_cbar_part(const float* Tbar, const float* w_v, float* part) {
  int c  = blockIdx.x * 256 + threadIdx.x;
  int e0 = blockIdx.y * 64;
  int h  = c >> 7;
  float acc[8];
#pragma unroll
  for (int b = 0; b < 8; ++b) acc[b] = 0.f;
  for (int e = e0; e < e0 + 64; ++e) {
    float wv = w_v[(size_t)e * 2048 + c];
#pragma unroll
    for (int b = 0; b < 8; ++b) acc[b] += Tbar[((size_t)b * 16 + h) * 2048 + e] * wv;
  }
#pragma unroll
  for (int b = 0; b < 8; ++b) part[((size_t)blockIdx.y * 8 + b) * 2048 + c] = acc[b];
}

// ---------------------------------------------------------------- vecmat partials over e: part[eb][b][c]
__global__ __launch_bounds__(256) void k_vecmat_part(const float* vin, const float* W, float* part) {
  int c  = blockIdx.x * 256 + threadIdx.x;
  int e0 = blockIdx.y * 64;
  float acc[8];
#pragma unroll
  for (int b = 0; b < 8; ++b) acc[b] = 0.f;
  for (int e = e0; e < e0 + 64; ++e) {
    float wv = W[(size_t)e * 2048 + c];
#pragma unroll
    for (int b = 0; b < 8; ++b) acc[b] += vin[b * 2048 + e] * wv;
  }
#pragma unroll
  for (int b = 0; b < 8; ++b) part[((size_t)blockIdx.y * 8 + b) * 2048 + c] = acc[b];
}

// ---------------------------------------------------------------- out = x + broadcast(outv)   (fp32)
__global__ __launch_bounds__(256) void k_resid(const float* x, const float* outv, float* out) {
  size_t i4 = (size_t)blockIdx.x * 256 + threadIdx.x;
  size_t total4 = (size_t)ROWS * 512;
  size_t stride = (size_t)gridDim.x * 256;
  for (; i4 < total4; i4 += stride) {
    int b  = (int)(i4 >> 21);               // 4096*512 float4 per batch
    int c4 = (int)(i4 & 511);
    float4 xv = ((const float4*)x)[i4];
    float4 ov = ((const float4*)outv)[b * 512 + c4];
    float4 o;
    o.x = xv.x + ov.x; o.y = xv.y + ov.y;
    o.z = xv.z + ov.z; o.w = xv.w + ov.w;
    ((float4*)out)[i4] = o;
  }
}

// ================================================================ launch
extern "C" void kernel_launch(void* const* d_in, const int* in_sizes, int n_in,
                              void* d_out, int out_size, void* d_ws, size_t ws_size,
                              hipStream_t stream) {
  const float* x       = (const float*)d_in[0];
  const float* ln_g    = (const float*)d_in[1];
  const float* ln_b    = (const float*)d_in[2];
  const float* latents = (const float*)d_in[3];
  const float* w_lq    = (const float*)d_in[4];
  const float* b_lq    = (const float*)d_in[5];
  const float* w_k     = (const float*)d_in[6];
  // const float* b_k  = (const float*)d_in[7];   // softmax-invariant, unused
  const float* w_v     = (const float*)d_in[8];
  const float* b_v     = (const float*)d_in[9];
  const float* w_lv    = (const float*)d_in[10];
  const float* b_lv    = (const float*)d_in[11];
  const float* w_out   = (const float*)d_in[12];
  const float* b_out   = (const float*)d_in[13];

  // d_out is fp32 [8,4096,2048] = 256 MB; first ~88 MB doubles as scratch,
  // all dead before k_resid overwrites the full buffer. outv lives in d_ws.
  char* base = (char*)d_out;
  float* scores = (float*)(base);                        // 33,554,432 B
  short* probs  = (short*)(base + 33554432);             // 16,777,216 B
  float* T      = (float*)(base + 50331648);             // 16,777,216 B
  float* q      = (float*)(base + 67108864);             //    131,072 B
  short* wq_t   = (short*)(base + 67239936);             //  1,048,576 B
  float* stats  = (float*)(base + 68288512);             //    262,144 B
  float* Tbar   = (float*)(base + 68550656);             //  1,048,576 B
  float* cbar   = (float*)(base + 69599232);             //     65,536 B
  float* pooled = (float*)(base + 69664768);             //     65,536 B
  float* part   = (float*)(base + 83886080);             //  4,194,304 B (80 MB mark)
  float* outv   = (float*)d_ws;                          //     65,536 B (read by k_resid)
  float* out    = (float*)d_out;

  k_q_part     <<<dim3(8, 32), 256, 0, stream>>>(latents, w_lq, part);
  k_reduce     <<<dim3(8, 16), 256, 0, stream>>>(part, b_lq, q, 16);
  k_stats      <<<32768, 256, 0, stream>>>(x, stats);
  k_wq         <<<2048, 256, 0, stream>>>(w_k, q, wq_t);
  k_scores     <<<dim3(64, 8), 256, 0, stream>>>(x, stats, ln_g, ln_b, wq_t, scores);
  k_softmax    <<<dim3(256, 8), 256, 0, stream>>>(scores, probs);
  k_T          <<<dim3(32, 8), 256, 0, stream>>>(x, stats, ln_g, ln_b, probs, T);
  k_tbar       <<<128, 256, 0, stream>>>(T, Tbar);
  k_cbar_part  <<<dim3(8, 32), 256, 0, stream>>>(Tbar, w_v, part);
  k_reduce     <<<dim3(8, 8), 256, 0, stream>>>(part, b_v, cbar, 8);
  k_vecmat_part<<<dim3(8, 32), 256, 0, stream>>>(cbar, w_lv, part);
  k_reduce     <<<dim3(8, 8), 256, 0, stream>>>(part, b_lv, pooled, 8);
  k_vecmat_part<<<dim3(8, 32), 256, 0, stream>>>(pooled, w_out, part);
  k_reduce     <<<dim3(8, 8), 256, 0, stream>>>(part, b_out, outv, 8);
  k_resid      <<<2048, 256, 0, stream>>>(x, outv, out);
}

// Round 4
// 527.902 us; speedup vs baseline: 3.7189x; 1.1552x over previous
//
#include <hip/hip_runtime.h>
#include <hip/hip_bf16.h>

// Problem constants
#define BB 8
#define SS 4096
#define DD 2048
#define HH 16
#define HDIM 128
#define LL 16
#define JJ 256           // HH*LL, j = h*16 + l
#define ROWS (BB*SS)     // 32768
#define LN_EPS 1e-5f

typedef __attribute__((ext_vector_type(8))) short short8;
typedef __attribute__((ext_vector_type(4))) float f32x4;

__device__ __forceinline__ unsigned short f2bf(float f) {
  unsigned int u = __builtin_bit_cast(unsigned int, f);
  u += 0x7fffu + ((u >> 16) & 1u);        // round-to-nearest-even
  return (unsigned short)(u >> 16);
}
__device__ __forceinline__ float bf2f(unsigned short u) {
  unsigned int v = ((unsigned int)u) << 16;
  return __builtin_bit_cast(float, v);
}

// ---------------------------------------------------------------- q partials: qpart[eb][l][c]
__global__ __launch_bounds__(256) void k_q_part(const float* latents, const float* w_lq, float* qpart) {
  int c  = blockIdx.x * 256 + threadIdx.x;  // 0..2047
  int e0 = blockIdx.y * 64;                 // 32 chunks
  float acc[16];
#pragma unroll
  for (int l = 0; l < 16; ++l) acc[l] = 0.f;
  for (int e = e0; e < e0 + 64; ++e) {
    float w = w_lq[(size_t)e * 2048 + c];
#pragma unroll
    for (int l = 0; l < 16; ++l) acc[l] += latents[l * 2048 + e] * w;
  }
#pragma unroll
  for (int l = 0; l < 16; ++l) qpart[((size_t)blockIdx.y * 16 + l) * 2048 + c] = acc[l];
}

// ---------------------------------------------------------------- 32-partial reduce: out[r][c] = bias[c] + sum_p part[p][r][c]
__global__ __launch_bounds__(256) void k_reduce(const float* part, const float* bias, float* out, int R) {
  int c = blockIdx.x * 256 + threadIdx.x;   // grid.x = 8
  int r = blockIdx.y;                       // grid.y = R
  float s = bias[c];
  for (int p = 0; p < 32; ++p) s += part[((size_t)p * R + r) * 2048 + c];
  out[r * 2048 + c] = s;
}

// ---------------------------------------------------------------- fused LN: h[row][e] = bf16(LN(x[row]))  (stats in-register)
__global__ __launch_bounds__(256) void k_lnT(const float* x, const float* ln_g, const float* ln_b,
                                             short* h) {
  int row = blockIdx.x;                     // 0..32767
  int t = threadIdx.x;
  const float4* xr = (const float4*)(x + (size_t)row * 2048);
  float4 v0 = xr[t * 2];
  float4 v1 = xr[t * 2 + 1];
  float s  = v0.x + v0.y + v0.z + v0.w + v1.x + v1.y + v1.z + v1.w;
  float s2 = v0.x*v0.x + v0.y*v0.y + v0.z*v0.z + v0.w*v0.w
           + v1.x*v1.x + v1.y*v1.y + v1.z*v1.z + v1.w*v1.w;
#pragma unroll
  for (int o = 32; o; o >>= 1) { s += __shfl_down(s, o); s2 += __shfl_down(s2, o); }
  __shared__ float red[8];
  int wid = t >> 6;
  if ((t & 63) == 0) { red[wid] = s; red[4 + wid] = s2; }
  __syncthreads();
  float ts  = red[0] + red[1] + red[2] + red[3];
  float ts2 = red[4] + red[5] + red[6] + red[7];
  float mu   = ts * (1.0f / 2048.0f);
  float var  = ts2 * (1.0f / 2048.0f) - mu * mu;
  float rstd = rsqrtf(var + LN_EPS);
  const float4* gp = (const float4*)ln_g;
  const float4* bp = (const float4*)ln_b;
  float4 g0 = gp[t * 2], g1 = gp[t * 2 + 1];
  float4 b0 = bp[t * 2], b1 = bp[t * 2 + 1];
  short8 o;
  o[0] = (short)f2bf((v0.x - mu) * rstd * g0.x + b0.x);
  o[1] = (short)f2bf((v0.y - mu) * rstd * g0.y + b0.y);
  o[2] = (short)f2bf((v0.z - mu) * rstd * g0.z + b0.z);
  o[3] = (short)f2bf((v0.w - mu) * rstd * g0.w + b0.w);
  o[4] = (short)f2bf((v1.x - mu) * rstd * g1.x + b1.x);
  o[5] = (short)f2bf((v1.y - mu) * rstd * g1.y + b1.y);
  o[6] = (short)f2bf((v1.z - mu) * rstd * g1.z + b1.z);
  o[7] = (short)f2bf((v1.w - mu) * rstd * g1.w + b1.w);
  ((short8*)(h + (size_t)row * 2048))[t] = o;
}

// ---------------------------------------------------------------- Wq_t[j][e] = (1/sqrt(128)) * sum_d w_k[e][h*128+d] * q[l][h*128+d]
__global__ __launch_bounds__(256) void k_wq(const float* w_k, const float* q, short* wq_t) {
  int e = blockIdx.x;                       // 0..2047
  __shared__ float wrow[2048];
  for (int i = threadIdx.x; i < 512; i += 256)
    ((float4*)wrow)[i] = ((const float4*)(w_k + (size_t)e * 2048))[i];
  __syncthreads();
  int j = threadIdx.x;
  int h = j >> 4, l = j & 15;
  const float* qrow = q + l * 2048 + h * 128;
  const float* wr = wrow + h * 128;
  float acc = 0.f;
#pragma unroll 8
  for (int d = 0; d < 128; ++d) acc += wr[d] * qrow[d];
  wq_t[(size_t)j * 2048 + e] = (short)f2bf(acc * 0.08838834764831845f);
}

// ---------------------------------------------------------------- scores[b][j][s] = Wq_t @ h^T  (h pre-LN'd bf16)
__global__ __launch_bounds__(256) void k_scores(const short* h, const short* wq_t, float* scores) {
  int s0 = blockIdx.x * 64;                 // s-tile
  int b  = blockIdx.y;
  __shared__ short lA[256 * 72];            // Wq_t tile [j][k], padded
  __shared__ short lB[64 * 72];             // h tile [s][k], padded
  int t = threadIdx.x, lane = t & 63, w = t >> 6;
  f32x4 zero = {0.f, 0.f, 0.f, 0.f};
  f32x4 acc[4][4];
#pragma unroll
  for (int m = 0; m < 4; ++m)
#pragma unroll
    for (int n = 0; n < 4; ++n) acc[m][n] = zero;

  int sr = t >> 2, ec = t & 3;              // B staging: row 0..63, 16-col chunk 0..3
  const short* hrow = h + ((size_t)(b * 4096 + s0 + sr)) * 2048;

  for (int k0 = 0; k0 < 2048; k0 += 64) {
    { // stage A: thread t = row j, 64 bf16
      const short8* src = (const short8*)(wq_t + (size_t)t * 2048 + k0);
      short8* dst = (short8*)(lA + t * 72);
#pragma unroll
      for (int i = 0; i < 8; ++i) dst[i] = src[i];
    }
    { // stage B: copy h bf16
      const short8* src = (const short8*)(hrow + k0 + ec * 16);
      short8* dstb = (short8*)(lB + sr * 72 + ec * 16);
      dstb[0] = src[0]; dstb[1] = src[1];
    }
    __syncthreads();
#pragma unroll
    for (int kk = 0; kk < 2; ++kk) {
      short8 afr[4];
#pragma unroll
      for (int m = 0; m < 4; ++m)
        afr[m] = *(const short8*)(lA + (w * 64 + m * 16 + (lane & 15)) * 72 + kk * 32 + (lane >> 4) * 8);
#pragma unroll
      for (int n = 0; n < 4; ++n) {
        short8 bfr = *(const short8*)(lB + (n * 16 + (lane & 15)) * 72 + kk * 32 + (lane >> 4) * 8);
#pragma unroll
        for (int m = 0; m < 4; ++m)
          acc[m][n] = __builtin_amdgcn_mfma_f32_16x16x32_bf16(afr[m], bfr, acc[m][n], 0, 0, 0);
      }
    }
    __syncthreads();
  }
  int r4 = (lane >> 4) * 4, cc = lane & 15;
#pragma unroll
  for (int m = 0; m < 4; ++m) {
    int j = w * 64 + m * 16 + r4;
#pragma unroll
    for (int n = 0; n < 4; ++n) {
      int s = s0 + n * 16 + cc;
      float* dst = scores + ((size_t)b * 256 + j) * 4096 + s;
#pragma unroll
      for (int i = 0; i < 4; ++i) dst[(size_t)i * 4096] = acc[m][n][i];
    }
  }
}

// ---------------------------------------------------------------- softmax pass A: per-row max + 1/(16*sum)
__global__ __launch_bounds__(256) void k_smax_a(const float* scores, float* msum) {
  int j = blockIdx.x, b = blockIdx.y;
  const float* row = scores + ((size_t)b * 256 + j) * 4096;
  float v[16];
  float mx = -1e30f;
#pragma unroll
  for (int i = 0; i < 16; ++i) { v[i] = row[threadIdx.x + 256 * i]; mx = fmaxf(mx, v[i]); }
#pragma unroll
  for (int o = 32; o; o >>= 1) mx = fmaxf(mx, __shfl_xor(mx, o));
  __shared__ float redm[4], reds[4];
  if ((threadIdx.x & 63) == 0) redm[threadIdx.x >> 6] = mx;
  __syncthreads();
  mx = fmaxf(fmaxf(redm[0], redm[1]), fmaxf(redm[2], redm[3]));
  float sum = 0.f;
#pragma unroll
  for (int i = 0; i < 16; ++i) sum += __expf(v[i] - mx);
#pragma unroll
  for (int o = 32; o; o >>= 1) sum += __shfl_xor(sum, o);
  if ((threadIdx.x & 63) == 0) reds[threadIdx.x >> 6] = sum;
  __syncthreads();
  if (threadIdx.x == 0) {
    sum = reds[0] + reds[1] + reds[2] + reds[3];
    msum[(b * 256 + j) * 2]     = mx;
    msum[(b * 256 + j) * 2 + 1] = 1.0f / (16.0f * sum);
  }
}

// ---------------------------------------------------------------- softmax pass B: pbar[b][h][s] = sum_l exp(sc-m)*inv16
__global__ __launch_bounds__(256) void k_smax_b(const float* scores, const float* msum, float* pbar) {
  int b = blockIdx.y, sc = blockIdx.x;      // 64 s-chunks of 64
  int t = threadIdx.x, lane = t & 63, jq = t >> 6;
  int s = sc * 64 + lane;
  const float* srow = scores + ((size_t)(b * 256 + jq * 64)) * 4096 + s;
  const float* ms = msum + (b * 256 + jq * 64) * 2;
  float acc[4] = {0.f, 0.f, 0.f, 0.f};
  for (int jj = 0; jj < 64; ++jj) {
    float m  = ms[jj * 2];
    float iv = ms[jj * 2 + 1];
    float v = __expf(srow[(size_t)jj * 4096] - m) * iv;
    acc[jj >> 4] += v;
  }
#pragma unroll
  for (int r = 0; r < 4; ++r)
    pbar[((size_t)b * 16 + jq * 4 + r) * 4096 + s] = acc[r];
}

// ---------------------------------------------------------------- Tbar partials: Tpart[sp][b][h][e] = sum_{s in chunk} pbar[h][s] h[s][e]
__global__ __launch_bounds__(256) void k_tbar2(const short* h, const float* pbar, float* Tpart) {
  int ec = blockIdx.x;                      // 0..1 (e-chunks of 1024)
  int sp = blockIdx.y;                      // 0..15 (s-chunks of 256)
  int b  = blockIdx.z;
  int t  = threadIdx.x;
  int e0 = ec * 1024 + t * 4;
  __shared__ float lp[16 * 256];            // pbar chunk [h][s]
  {
    int hh = t >> 4, so = (t & 15) * 16;
    const float4* src = (const float4*)(pbar + ((size_t)b * 16 + hh) * 4096 + sp * 256 + so);
    float4* dst = (float4*)(lp + hh * 256 + so);
#pragma unroll
    for (int i = 0; i < 4; ++i) dst[i] = src[i];
  }
  __syncthreads();
  f32x4 acc[16];
#pragma unroll
  for (int hh = 0; hh < 16; ++hh) acc[hh] = (f32x4){0.f, 0.f, 0.f, 0.f};

  const short* hbase = h + ((size_t)(b * 4096 + sp * 256)) * 2048 + e0;
  for (int si = 0; si < 256; si += 4) {
    float hv[4][4];
#pragma unroll
    for (int r = 0; r < 4; ++r) {
      short4 hh4 = *(const short4*)(hbase + (size_t)(si + r) * 2048);
      hv[r][0] = bf2f((unsigned short)hh4.x);
      hv[r][1] = bf2f((unsigned short)hh4.y);
      hv[r][2] = bf2f((unsigned short)hh4.z);
      hv[r][3] = bf2f((unsigned short)hh4.w);
    }
#pragma unroll
    for (int hh = 0; hh < 16; ++hh) {
      float4 ph = *(const float4*)(lp + hh * 256 + si);
#pragma unroll
      for (int c = 0; c < 4; ++c)
        acc[hh][c] += ph.x * hv[0][c] + ph.y * hv[1][c] + ph.z * hv[2][c] + ph.w * hv[3][c];
    }
  }
#pragma unroll
  for (int hh = 0; hh < 16; ++hh)
    *(f32x4*)(Tpart + ((size_t)((sp * 8 + b) * 16 + hh)) * 2048 + e0) = acc[hh];
}

// ---------------------------------------------------------------- Tbar[bh][e] = sum_sp Tpart[sp][bh][e]
__global__ __launch_bounds__(256) void k_tred(const float* Tpart, float* Tbar) {
  int bh = blockIdx.x;                      // 0..127 (= b*16+h)
  for (int e = threadIdx.x; e < 2048; e += 256) {
    float s = 0.f;
#pragma unroll
    for (int p = 0; p < 16; ++p) s += Tpart[((size_t)p * 128 + bh) * 2048 + e];
    Tbar[(size_t)bh * 2048 + e] = s;
  }
}

// ---------------------------------------------------------------- cbar partials over e: part[eb][b][c]
__global__ __launch_bounds__(256) void k_cbar_part(const float* Tbar, const float* w_v, float* part) {
  int c  = blockIdx.x * 256 + threadIdx.x;
  int e0 = blockIdx.y * 64;
  int h  = c >> 7;
  float acc[8];
#pragma unroll
  for (int b = 0; b < 8; ++b) acc[b] = 0.f;
  for (int e = e0; e < e0 + 64; ++e) {
    float wv = w_v[(size_t)e * 2048 + c];
#pragma unroll
    for (int b = 0; b < 8; ++b) acc[b] += Tbar[((size_t)b * 16 + h) * 2048 + e] * wv;
  }
#pragma unroll
  for (int b = 0; b < 8; ++b) part[((size_t)blockIdx.y * 8 + b) * 2048 + c] = acc[b];
}

// ---------------------------------------------------------------- vecmat partials over e: part[eb][b][c]
__global__ __launch_bounds__(256) void k_vecmat_part(const float* vin, const float* W, float* part) {
  int c  = blockIdx.x * 256 + threadIdx.x;
  int e0 = blockIdx.y * 64;
  float acc[8];
#pragma unroll
  for (int b = 0; b < 8; ++b) acc[b] = 0.f;
  for (int e = e0; e < e0 + 64; ++e) {
    float wv = W[(size_t)e * 2048 + c];
#pragma unroll
    for (int b = 0; b < 8; ++b) acc[b] += vin[b * 2048 + e] * wv;
  }
#pragma unroll
  for (int b = 0; b < 8; ++b) part[((size_t)blockIdx.y * 8 + b) * 2048 + c] = acc[b];
}

// ---------------------------------------------------------------- out = x + broadcast(outv)   (fp32)
__global__ __launch_bounds__(256) void k_resid(const float* x, const float* outv, float* out) {
  size_t i4 = (size_t)blockIdx.x * 256 + threadIdx.x;
  size_t total4 = (size_t)ROWS * 512;
  size_t stride = (size_t)gridDim.x * 256;
  for (; i4 < total4; i4 += stride) {
    int b  = (int)(i4 >> 21);               // 4096*512 float4 per batch
    int c4 = (int)(i4 & 511);
    float4 xv = ((const float4*)x)[i4];
    float4 ov = ((const float4*)outv)[b * 512 + c4];
    float4 o;
    o.x = xv.x + ov.x; o.y = xv.y + ov.y;
    o.z = xv.z + ov.z; o.w = xv.w + ov.w;
    ((float4*)out)[i4] = o;
  }
}

// ================================================================ launch
extern "C" void kernel_launch(void* const* d_in, const int* in_sizes, int n_in,
                              void* d_out, int out_size, void* d_ws, size_t ws_size,
                              hipStream_t stream) {
  const float* x       = (const float*)d_in[0];
  const float* ln_g    = (const float*)d_in[1];
  const float* ln_b    = (const float*)d_in[2];
  const float* latents = (const float*)d_in[3];
  const float* w_lq    = (const float*)d_in[4];
  const float* b_lq    = (const float*)d_in[5];
  const float* w_k     = (const float*)d_in[6];
  // const float* b_k  = (const float*)d_in[7];   // softmax-invariant, unused
  const float* w_v     = (const float*)d_in[8];
  const float* b_v     = (const float*)d_in[9];
  const float* w_lv    = (const float*)d_in[10];
  const float* b_lv    = (const float*)d_in[11];
  const float* w_out   = (const float*)d_in[12];
  const float* b_out   = (const float*)d_in[13];

  // d_out is fp32 [8,4096,2048] = 256 MB; first ~193 MB doubles as scratch,
  // all dead before k_resid overwrites the full buffer. outv lives in d_ws.
  char* base = (char*)d_out;
  float* scores = (float*)(base);                        //  33,554,432 B
  short* h      = (short*)(base + 33554432);             // 134,217,728 B (bf16 LN(x))
  float* Tpart  = (float*)(base + 167772160);            //  16,777,216 B
  float* pbar   = (float*)(base + 184549376);            //   2,097,152 B
  float* msum   = (float*)(base + 186646528);            //      16,384 B
  float* q      = (float*)(base + 186662912);            //     131,072 B
  short* wq_t   = (short*)(base + 186793984);            //   1,048,576 B
  float* Tbar   = (float*)(base + 187842560);            //     524,288 B
  float* cbar   = (float*)(base + 188366848);            //      65,536 B
  float* pooled = (float*)(base + 188432384);            //      65,536 B
  float* part   = (float*)(base + 188497920);            //   4,194,304 B
  float* outv   = (float*)d_ws;                          //      65,536 B
  float* out    = (float*)d_out;

  k_q_part     <<<dim3(8, 32), 256, 0, stream>>>(latents, w_lq, part);
  k_reduce     <<<dim3(8, 16), 256, 0, stream>>>(part, b_lq, q, 16);
  k_lnT        <<<32768, 256, 0, stream>>>(x, ln_g, ln_b, h);
  k_wq         <<<2048, 256, 0, stream>>>(w_k, q, wq_t);
  k_scores     <<<dim3(64, 8), 256, 0, stream>>>(h, wq_t, scores);
  k_smax_a     <<<dim3(256, 8), 256, 0, stream>>>(scores, msum);
  k_smax_b     <<<dim3(64, 8), 256, 0, stream>>>(scores, msum, pbar);
  k_tbar2      <<<dim3(2, 16, 8), 256, 0, stream>>>(h, pbar, Tpart);
  k_tred       <<<128, 256, 0, stream>>>(Tpart, Tbar);
  k_cbar_part  <<<dim3(8, 32), 256, 0, stream>>>(Tbar, w_v, part);
  k_reduce     <<<dim3(8, 8), 256, 0, stream>>>(part, b_v, cbar, 8);
  k_vecmat_part<<<dim3(8, 32), 256, 0, stream>>>(cbar, w_lv, part);
  k_reduce     <<<dim3(8, 8), 256, 0, stream>>>(part, b_lv, pooled, 8);
  k_vecmat_part<<<dim3(8, 32), 256, 0, stream>>>(pooled, w_out, part);
  k_reduce     <<<dim3(8, 8), 256, 0, stream>>>(part, b_out, outv, 8);
  k_resid      <<<2048, 256, 0, stream>>>(x, outv, out);
}

// Round 5
// 469.497 us; speedup vs baseline: 4.1815x; 1.1244x over previous
//
#include <hip/hip_runtime.h>
#include <hip/hip_bf16.h>

// Problem constants
#define BB 8
#define SS 4096
#define DD 2048
#define HH 16
#define HDIM 128
#define LL 16
#define JJ 256           // HH*LL, j = h*16 + l
#define ROWS (BB*SS)     // 32768
#define LN_EPS 1e-5f

typedef __attribute__((ext_vector_type(8))) short short8;
typedef __attribute__((ext_vector_type(4))) float f32x4;

typedef __attribute__((address_space(1))) const unsigned int gu32;
typedef __attribute__((address_space(3))) unsigned int lu32;
__device__ __forceinline__ void async16(const void* g, void* l) {
  __builtin_amdgcn_global_load_lds((gu32*)g, (lu32*)l, 16, 0, 0);
}

__device__ __forceinline__ unsigned short f2bf(float f) {
  unsigned int u = __builtin_bit_cast(unsigned int, f);
  u += 0x7fffu + ((u >> 16) & 1u);        // round-to-nearest-even
  return (unsigned short)(u >> 16);
}
__device__ __forceinline__ float bf2f(unsigned short u) {
  unsigned int v = ((unsigned int)u) << 16;
  return __builtin_bit_cast(float, v);
}

// ---------------------------------------------------------------- q partials: qpart[eb][l][c]
__global__ __launch_bounds__(256) void k_q_part(const float* latents, const float* w_lq, float* qpart) {
  int c  = blockIdx.x * 256 + threadIdx.x;  // 0..2047
  int e0 = blockIdx.y * 64;                 // 32 chunks
  float acc[16];
#pragma unroll
  for (int l = 0; l < 16; ++l) acc[l] = 0.f;
  for (int e = e0; e < e0 + 64; ++e) {
    float w = w_lq[(size_t)e * 2048 + c];
#pragma unroll
    for (int l = 0; l < 16; ++l) acc[l] += latents[l * 2048 + e] * w;
  }
#pragma unroll
  for (int l = 0; l < 16; ++l) qpart[((size_t)blockIdx.y * 16 + l) * 2048 + c] = acc[l];
}

// ---------------------------------------------------------------- 32-partial reduce: out[r][c] = bias[c] + sum_p part[p][r][c]
__global__ __launch_bounds__(256) void k_reduce(const float* part, const float* bias, float* out, int R) {
  int c = blockIdx.x * 256 + threadIdx.x;   // grid.x = 8
  int r = blockIdx.y;                       // grid.y = R
  float s = bias[c];
  for (int p = 0; p < 32; ++p) s += part[((size_t)p * R + r) * 2048 + c];
  out[r * 2048 + c] = s;
}

// ---------------------------------------------------------------- fused LN: h[row][e] = bf16(LN(x[row]))
__global__ __launch_bounds__(256) void k_lnT(const float* x, const float* ln_g, const float* ln_b,
                                             short* h) {
  int row = blockIdx.x;                     // 0..32767
  int t = threadIdx.x;
  const float4* xr = (const float4*)(x + (size_t)row * 2048);
  float4 v0 = xr[t * 2];
  float4 v1 = xr[t * 2 + 1];
  float s  = v0.x + v0.y + v0.z + v0.w + v1.x + v1.y + v1.z + v1.w;
  float s2 = v0.x*v0.x + v0.y*v0.y + v0.z*v0.z + v0.w*v0.w
           + v1.x*v1.x + v1.y*v1.y + v1.z*v1.z + v1.w*v1.w;
#pragma unroll
  for (int o = 32; o; o >>= 1) { s += __shfl_down(s, o); s2 += __shfl_down(s2, o); }
  __shared__ float red[8];
  int wid = t >> 6;
  if ((t & 63) == 0) { red[wid] = s; red[4 + wid] = s2; }
  __syncthreads();
  float ts  = red[0] + red[1] + red[2] + red[3];
  float ts2 = red[4] + red[5] + red[6] + red[7];
  float mu   = ts * (1.0f / 2048.0f);
  float var  = ts2 * (1.0f / 2048.0f) - mu * mu;
  float rstd = rsqrtf(var + LN_EPS);
  const float4* gp = (const float4*)ln_g;
  const float4* bp = (const float4*)ln_b;
  float4 g0 = gp[t * 2], g1 = gp[t * 2 + 1];
  float4 b0 = bp[t * 2], b1 = bp[t * 2 + 1];
  short8 o;
  o[0] = (short)f2bf((v0.x - mu) * rstd * g0.x + b0.x);
  o[1] = (short)f2bf((v0.y - mu) * rstd * g0.y + b0.y);
  o[2] = (short)f2bf((v0.z - mu) * rstd * g0.z + b0.z);
  o[3] = (short)f2bf((v0.w - mu) * rstd * g0.w + b0.w);
  o[4] = (short)f2bf((v1.x - mu) * rstd * g1.x + b1.x);
  o[5] = (short)f2bf((v1.y - mu) * rstd * g1.y + b1.y);
  o[6] = (short)f2bf((v1.z - mu) * rstd * g1.z + b1.z);
  o[7] = (short)f2bf((v1.w - mu) * rstd * g1.w + b1.w);
  ((short8*)(h + (size_t)row * 2048))[t] = o;
}

// ---------------------------------------------------------------- Wq_t[j][e]
__global__ __launch_bounds__(256) void k_wq(const float* w_k, const float* q, short* wq_t) {
  int e = blockIdx.x;                       // 0..2047
  __shared__ float wrow[2048];
  for (int i = threadIdx.x; i < 512; i += 256)
    ((float4*)wrow)[i] = ((const float4*)(w_k + (size_t)e * 2048))[i];
  __syncthreads();
  int j = threadIdx.x;
  int h = j >> 4, l = j & 15;
  const float* qrow = q + l * 2048 + h * 128;
  const float* wr = wrow + h * 128;
  float acc = 0.f;
#pragma unroll 8
  for (int d = 0; d < 128; ++d) acc += wr[d] * qrow[d];
  wq_t[(size_t)j * 2048 + e] = (short)f2bf(acc * 0.08838834764831845f);
}

// ---------------------------------------------------------------- scores[b][j][s] = Wq_t @ h^T
// 2-phase pipeline: global_load_lds (16B) into double-buffered linear LDS with
// XOR source-swizzle; one barrier per K-step; stage k+1 issued before compute k.
__global__ __launch_bounds__(256, 2) void k_scores(const short* h, const short* wq_t, float* scores) {
  int s0 = blockIdx.x * 64;                 // s-tile
  int b  = blockIdx.y;
  __shared__ short lds[2 * 16384 + 2 * 4096];   // A dbuf 2x[256][64], B dbuf 2x[64][64], linear
  int t = threadIdx.x, lane = t & 63, w = t >> 6;
  f32x4 zero = {0.f, 0.f, 0.f, 0.f};
  f32x4 acc[4][4];
#pragma unroll
  for (int m = 0; m < 4; ++m)
#pragma unroll
    for (int n = 0; n < 4; ++n) acc[m][n] = zero;

  // staging geometry: dest chunk (16B) = i*256 + w*64 + lane  -> row = i*32 + w*8 + (lane>>3), kc_slot = lane&7
  // slot (row, kc) holds global (row, kc ^ (row&7)); row&7 == (lane>>3)&7
  int jlo = w * 8 + (lane >> 3);
  int kcs = (lane & 7) ^ ((lane >> 3) & 7);           // source k-chunk for this lane's slot
  const short* hbase = h + ((size_t)(b * 4096 + s0)) * 2048;
  // ds_read swizzled k-offset (shorts): kc_r = (kk*4 + (lane>>4)) ^ (lane&7)
  int koff0 = (((lane >> 4)) ^ (lane & 7)) * 8;
  int koff1 = ((4 + (lane >> 4)) ^ (lane & 7)) * 8;

  int cur = 0;
  // prologue: stage k0=0 into buf 0
  {
#pragma unroll
    for (int i = 0; i < 8; ++i)
      async16(wq_t + (size_t)(i * 32 + jlo) * 2048 + kcs * 8,
              lds + (size_t)(i * 256 + w * 64) * 8);
#pragma unroll
    for (int i = 0; i < 2; ++i)
      async16(hbase + (size_t)(i * 32 + jlo) * 2048 + kcs * 8,
              lds + 32768 + (size_t)(i * 256 + w * 64) * 8);
  }
  __syncthreads();

  for (int it = 0; it < 32; ++it) {
    if (it < 31) {                       // stage next K-step into other buffer
      int k0 = (it + 1) * 64;
      short* lA1 = lds + (cur ^ 1) * 16384;
      short* lB1 = lds + 32768 + (cur ^ 1) * 4096;
#pragma unroll
      for (int i = 0; i < 8; ++i)
        async16(wq_t + (size_t)(i * 32 + jlo) * 2048 + k0 + kcs * 8,
                lA1 + (size_t)(i * 256 + w * 64) * 8);
#pragma unroll
      for (int i = 0; i < 2; ++i)
        async16(hbase + (size_t)(i * 32 + jlo) * 2048 + k0 + kcs * 8,
                lB1 + (size_t)(i * 256 + w * 64) * 8);
    }
    const short* lA = lds + cur * 16384;
    const short* lB = lds + 32768 + cur * 4096;
#pragma unroll
    for (int kk = 0; kk < 2; ++kk) {
      int ko = kk ? koff1 : koff0;
      short8 afr[4];
#pragma unroll
      for (int m = 0; m < 4; ++m)
        afr[m] = *(const short8*)(lA + (w * 64 + m * 16 + (lane & 15)) * 64 + ko);
#pragma unroll
      for (int n = 0; n < 4; ++n) {
        short8 bfr = *(const short8*)(lB + (n * 16 + (lane & 15)) * 64 + ko);
#pragma unroll
        for (int m = 0; m < 4; ++m)
          acc[m][n] = __builtin_amdgcn_mfma_f32_16x16x32_bf16(afr[m], bfr, acc[m][n], 0, 0, 0);
      }
    }
    __syncthreads();                     // drains vmcnt(0): next buffer ready, this buffer free
    cur ^= 1;
  }

  int r4 = (lane >> 4) * 4, cc = lane & 15;
#pragma unroll
  for (int m = 0; m < 4; ++m) {
    int j = w * 64 + m * 16 + r4;
#pragma unroll
    for (int n = 0; n < 4; ++n) {
      int s = s0 + n * 16 + cc;
      float* dst = scores + ((size_t)b * 256 + j) * 4096 + s;
#pragma unroll
      for (int i = 0; i < 4; ++i) dst[(size_t)i * 4096] = acc[m][n][i];
    }
  }
}

// ---------------------------------------------------------------- softmax pass A: per-row max + 1/(16*sum)
__global__ __launch_bounds__(256) void k_smax_a(const float* scores, float* msum) {
  int j = blockIdx.x, b = blockIdx.y;
  const float* row = scores + ((size_t)b * 256 + j) * 4096;
  float v[16];
  float mx = -1e30f;
#pragma unroll
  for (int i = 0; i < 16; ++i) { v[i] = row[threadIdx.x + 256 * i]; mx = fmaxf(mx, v[i]); }
#pragma unroll
  for (int o = 32; o; o >>= 1) mx = fmaxf(mx, __shfl_xor(mx, o));
  __shared__ float redm[4], reds[4];
  if ((threadIdx.x & 63) == 0) redm[threadIdx.x >> 6] = mx;
  __syncthreads();
  mx = fmaxf(fmaxf(redm[0], redm[1]), fmaxf(redm[2], redm[3]));
  float sum = 0.f;
#pragma unroll
  for (int i = 0; i < 16; ++i) sum += __expf(v[i] - mx);
#pragma unroll
  for (int o = 32; o; o >>= 1) sum += __shfl_xor(sum, o);
  if ((threadIdx.x & 63) == 0) reds[threadIdx.x >> 6] = sum;
  __syncthreads();
  if (threadIdx.x == 0) {
    sum = reds[0] + reds[1] + reds[2] + reds[3];
    msum[(b * 256 + j) * 2]     = mx;
    msum[(b * 256 + j) * 2 + 1] = 1.0f / (16.0f * sum);
  }
}

// ---------------------------------------------------------------- softmax pass B: pbar[b][h][s] = sum_l exp(sc-m)*inv16
__global__ __launch_bounds__(256) void k_smax_b(const float* scores, const float* msum, float* pbar) {
  int b = blockIdx.y, sc = blockIdx.x;      // 64 s-chunks of 64
  int t = threadIdx.x, lane = t & 63, jq = t >> 6;
  int s = sc * 64 + lane;
  const float* srow = scores + ((size_t)(b * 256 + jq * 64)) * 4096 + s;
  const float* ms = msum + (b * 256 + jq * 64) * 2;
  float acc[4] = {0.f, 0.f, 0.f, 0.f};
  for (int jj = 0; jj < 64; ++jj) {
    float m  = ms[jj * 2];
    float iv = ms[jj * 2 + 1];
    float v = __expf(srow[(size_t)jj * 4096] - m) * iv;
    acc[jj >> 4] += v;
  }
#pragma unroll
  for (int r = 0; r < 4; ++r)
    pbar[((size_t)b * 16 + jq * 4 + r) * 4096 + s] = acc[r];
}

// ---------------------------------------------------------------- Tbar partials: Tpart[sp][b][h][e]
__global__ __launch_bounds__(256) void k_tbar2(const short* h, const float* pbar, float* Tpart) {
  int ec = blockIdx.x;                      // 0..1 (e-chunks of 1024)
  int sp = blockIdx.y;                      // 0..15 (s-chunks of 256)
  int b  = blockIdx.z;
  int t  = threadIdx.x;
  int e0 = ec * 1024 + t * 4;
  __shared__ float lp[16 * 256];            // pbar chunk [h][s]
  {
    int hh = t >> 4, so = (t & 15) * 16;
    const float4* src = (const float4*)(pbar + ((size_t)b * 16 + hh) * 4096 + sp * 256 + so);
    float4* dst = (float4*)(lp + hh * 256 + so);
#pragma unroll
    for (int i = 0; i < 4; ++i) dst[i] = src[i];
  }
  __syncthreads();
  f32x4 acc[16];
#pragma unroll
  for (int hh = 0; hh < 16; ++hh) acc[hh] = (f32x4){0.f, 0.f, 0.f, 0.f};

  const short* hbase = h + ((size_t)(b * 4096 + sp * 256)) * 2048 + e0;
  for (int si = 0; si < 256; si += 4) {
    float hv[4][4];
#pragma unroll
    for (int r = 0; r < 4; ++r) {
      short4 hh4 = *(const short4*)(hbase + (size_t)(si + r) * 2048);
      hv[r][0] = bf2f((unsigned short)hh4.x);
      hv[r][1] = bf2f((unsigned short)hh4.y);
      hv[r][2] = bf2f((unsigned short)hh4.z);
      hv[r][3] = bf2f((unsigned short)hh4.w);
    }
#pragma unroll
    for (int hh = 0; hh < 16; ++hh) {
      float4 ph = *(const float4*)(lp + hh * 256 + si);
#pragma unroll
      for (int c = 0; c < 4; ++c)
        acc[hh][c] += ph.x * hv[0][c] + ph.y * hv[1][c] + ph.z * hv[2][c] + ph.w * hv[3][c];
    }
  }
#pragma unroll
  for (int hh = 0; hh < 16; ++hh)
    *(f32x4*)(Tpart + ((size_t)((sp * 8 + b) * 16 + hh)) * 2048 + e0) = acc[hh];
}

// ---------------------------------------------------------------- Tbar[bh][e] = sum_sp Tpart[sp][bh][e]
__global__ __launch_bounds__(256) void k_tred(const float* Tpart, float* Tbar) {
  int bh = blockIdx.x;                      // 0..127 (= b*16+h)
  for (int e = threadIdx.x; e < 2048; e += 256) {
    float s = 0.f;
#pragma unroll
    for (int p = 0; p < 16; ++p) s += Tpart[((size_t)p * 128 + bh) * 2048 + e];
    Tbar[(size_t)bh * 2048 + e] = s;
  }
}

// ---------------------------------------------------------------- cbar partials over e: part[eb][b][c]
__global__ __launch_bounds__(256) void k_cbar_part(const float* Tbar, const float* w_v, float* part) {
  int c  = blockIdx.x * 256 + threadIdx.x;
  int e0 = blockIdx.y * 64;
  int h  = c >> 7;
  float acc[8];
#pragma unroll
  for (int b = 0; b < 8; ++b) acc[b] = 0.f;
  for (int e = e0; e < e0 + 64; ++e) {
    float wv = w_v[(size_t)e * 2048 + c];
#pragma unroll
    for (int b = 0; b < 8; ++b) acc[b] += Tbar[((size_t)b * 16 + h) * 2048 + e] * wv;
  }
#pragma unroll
  for (int b = 0; b < 8; ++b) part[((size_t)blockIdx.y * 8 + b) * 2048 + c] = acc[b];
}

// ---------------------------------------------------------------- vecmat partials over e: part[eb][b][c]
__global__ __launch_bounds__(256) void k_vecmat_part(const float* vin, const float* W, float* part) {
  int c  = blockIdx.x * 256 + threadIdx.x;
  int e0 = blockIdx.y * 64;
  float acc[8];
#pragma unroll
  for (int b = 0; b < 8; ++b) acc[b] = 0.f;
  for (int e = e0; e < e0 + 64; ++e) {
    float wv = W[(size_t)e * 2048 + c];
#pragma unroll
    for (int b = 0; b < 8; ++b) acc[b] += vin[b * 2048 + e] * wv;
  }
#pragma unroll
  for (int b = 0; b < 8; ++b) part[((size_t)blockIdx.y * 8 + b) * 2048 + c] = acc[b];
}

// ---------------------------------------------------------------- out = x + broadcast(outv)   (fp32)
__global__ __launch_bounds__(256) void k_resid(const float* x, const float* outv, float* out) {
  size_t i4 = (size_t)blockIdx.x * 256 + threadIdx.x;
  size_t total4 = (size_t)ROWS * 512;
  size_t stride = (size_t)gridDim.x * 256;
  for (; i4 < total4; i4 += stride) {
    int b  = (int)(i4 >> 21);               // 4096*512 float4 per batch
    int c4 = (int)(i4 & 511);
    float4 xv = ((const float4*)x)[i4];
    float4 ov = ((const float4*)outv)[b * 512 + c4];
    float4 o;
    o.x = xv.x + ov.x; o.y = xv.y + ov.y;
    o.z = xv.z + ov.z; o.w = xv.w + ov.w;
    ((float4*)out)[i4] = o;
  }
}

// ================================================================ launch
extern "C" void kernel_launch(void* const* d_in, const int* in_sizes, int n_in,
                              void* d_out, int out_size, void* d_ws, size_t ws_size,
                              hipStream_t stream) {
  const float* x       = (const float*)d_in[0];
  const float* ln_g    = (const float*)d_in[1];
  const float* ln_b    = (const float*)d_in[2];
  const float* latents = (const float*)d_in[3];
  const float* w_lq    = (const float*)d_in[4];
  const float* b_lq    = (const float*)d_in[5];
  const float* w_k     = (const float*)d_in[6];
  // const float* b_k  = (const float*)d_in[7];   // softmax-invariant, unused
  const float* w_v     = (const float*)d_in[8];
  const float* b_v     = (const float*)d_in[9];
  const float* w_lv    = (const float*)d_in[10];
  const float* b_lv    = (const float*)d_in[11];
  const float* w_out   = (const float*)d_in[12];
  const float* b_out   = (const float*)d_in[13];

  // d_out is fp32 [8,4096,2048] = 256 MB; first ~193 MB doubles as scratch,
  // all dead before k_resid overwrites the full buffer. outv lives in d_ws.
  char* base = (char*)d_out;
  float* scores = (float*)(base);                        //  33,554,432 B
  short* h      = (short*)(base + 33554432);             // 134,217,728 B (bf16 LN(x))
  float* Tpart  = (float*)(base + 167772160);            //  16,777,216 B
  float* pbar   = (float*)(base + 184549376);            //   2,097,152 B
  float* msum   = (float*)(base + 186646528);            //      16,384 B
  float* q      = (float*)(base + 186662912);            //     131,072 B
  short* wq_t   = (short*)(base + 186793984);            //   1,048,576 B
  float* Tbar   = (float*)(base + 187842560);            //     524,288 B
  float* cbar   = (float*)(base + 188366848);            //      65,536 B
  float* pooled = (float*)(base + 188432384);            //      65,536 B
  float* part   = (float*)(base + 188497920);            //   4,194,304 B
  float* outv   = (float*)d_ws;                          //      65,536 B
  float* out    = (float*)d_out;

  k_q_part     <<<dim3(8, 32), 256, 0, stream>>>(latents, w_lq, part);
  k_reduce     <<<dim3(8, 16), 256, 0, stream>>>(part, b_lq, q, 16);
  k_lnT        <<<32768, 256, 0, stream>>>(x, ln_g, ln_b, h);
  k_wq         <<<2048, 256, 0, stream>>>(w_k, q, wq_t);
  k_scores     <<<dim3(64, 8), 256, 0, stream>>>(h, wq_t, scores);
  k_smax_a     <<<dim3(256, 8), 256, 0, stream>>>(scores, msum);
  k_smax_b     <<<dim3(64, 8), 256, 0, stream>>>(scores, msum, pbar);
  k_tbar2      <<<dim3(2, 16, 8), 256, 0, stream>>>(h, pbar, Tpart);
  k_tred       <<<128, 256, 0, stream>>>(Tpart, Tbar);
  k_cbar_part  <<<dim3(8, 32), 256, 0, stream>>>(Tbar, w_v, part);
  k_reduce     <<<dim3(8, 8), 256, 0, stream>>>(part, b_v, cbar, 8);
  k_vecmat_part<<<dim3(8, 32), 256, 0, stream>>>(cbar, w_lv, part);
  k_reduce     <<<dim3(8, 8), 256, 0, stream>>>(part, b_lv, pooled, 8);
  k_vecmat_part<<<dim3(8, 32), 256, 0, stream>>>(pooled, w_out, part);
  k_reduce     <<<dim3(8, 8), 256, 0, stream>>>(part, b_out, outv, 8);
  k_resid      <<<2048, 256, 0, stream>>>(x, outv, out);
}